// Round 8
// baseline (487.211 us; speedup 1.0000x reference)
//
#include <hip/hip_runtime.h>
#include <math.h>

// DigitCaps dynamic routing, fused/recompute formulation.
// u: [512,1152,8] f32, W: [1152,10,8,16] f32, out v: [512,10,16] f32.
// u_hat is NEVER materialized (377 MB). Routing logits are linear in v:
//   b_t[b,i,j] = sum_d u_hat[b,i,j,d] * Vsum[b,j,d],  Vsum = v1+...+v_{t-1}
// so each pass recomputes u_hat once from u,W and needs only Vsum (327 KB).
//
// R8: R1's proven shape (EP=12 b128 W reads, plain staging, lb-capped VGPR,
// clean 65/79 MB traffic) with ONE change: the u LDS tile is removed.
// u is read directly from global per (batch, ii): all 16 d-lanes of a
// bl-group hit the same 16 B -> coalesced broadcast; per-block u footprint
// is 16 KB -> L1-resident. This kills u ds_write/ds_read + 4.6 KB LDS:
//   LDS 35328 -> 30720 B  =>  5 blocks/CU, grid 1152 <= 1280 resident, no tail.
// R7 lesson: NO register prefetch across compute (spill storm, WRITE 189MB).
// launch_bounds(256,5) caps VGPR at 102 >> measured 64 for this body.

#define B_  512
#define NI  1152
#define NO  10
#define DI  8
#define DO  16

constexpr int TB      = 32;              // batches per block (2 per thread)
constexpr int TI      = 4;               // i's per staged chunk
constexpr int CHUNKS  = 4;               // chunks per block -> 16 i per block
constexpr int IGROUPS = NI / (TI * CHUNKS);   // 72
constexpr int EP      = 12;              // padded e-stride: rows 48B, 16B aligned

// LDS: Wt 4*10*16*12 = 7680 f (30720 B) only
// -> 5 blocks/CU (153.6 KB of 160 KB), 20 waves/CU; VGPR ~64 x 5 waves <= pool ok

// all-lanes sum over each aligned 16-lane group (d-lanes), DPP only (no LDS traffic)
__device__ __forceinline__ float row_allsum16(float x)
{
    union F { float f; int i; } a, t;
    a.f = x;  // quad_perm [1,0,3,2] : xor 1
    t.i = __builtin_amdgcn_update_dpp(0, a.i, 0xB1, 0xF, 0xF, true);  x += t.f;
    a.f = x;  // quad_perm [2,3,0,1] : xor 2
    t.i = __builtin_amdgcn_update_dpp(0, a.i, 0x4E, 0xF, 0xF, true);  x += t.f;
    a.f = x;  // row_ror:4
    t.i = __builtin_amdgcn_update_dpp(0, a.i, 0x124, 0xF, 0xF, true); x += t.f;
    a.f = x;  // row_ror:8
    t.i = __builtin_amdgcn_update_dpp(0, a.i, 0x128, 0xF, 0xF, true); x += t.f;
    return x; // every lane in the 16-group now holds the full 16-sum
}

template<bool FIRST>
__global__ __launch_bounds__(256, 5)
void routing_pass(const float* __restrict__ u, const float* __restrict__ W,
                  const float* __restrict__ vsum, float* __restrict__ s)
{
    __shared__ float wt[TI * NO * DO * EP];   // 7680 floats

    const int tid = threadIdx.x;
    const int bl  = tid >> 4;      // local batch slot 0..15
    const int d   = tid & 15;      // output dim 0..15
    const int bg0 = blockIdx.y * TB + bl;
    const int bg1 = bg0 + 16;

    // per-thread u row bases (i-offset added per chunk/ii)
    const float* u0 = u + (size_t)bg0 * (NI * DI);
    const float* u1 = u + (size_t)bg1 * (NI * DI);

    float vs0[NO], vs1[NO];
    if (!FIRST) {
        #pragma unroll
        for (int j = 0; j < NO; ++j) {
            vs0[j] = vsum[((size_t)bg0 * NO + j) * DO + d];
            vs1[j] = vsum[((size_t)bg1 * NO + j) * DO + d];
        }
    }
    float s0[NO], s1[NO];
    #pragma unroll
    for (int j = 0; j < NO; ++j) { s0[j] = 0.f; s1[j] = 0.f; }

    for (int c = 0; c < CHUNKS; ++c) {
        const int i0 = (blockIdx.x + c * IGROUPS) * TI;

        // ---- stage W chunk (contiguous 5120 floats = 5 x 1024, unguarded) into
        //      LDS transposed to wt[((ii*10+j)*16+d)*EP + e]  (R1 shape)
        {
            const float* wg = W + (size_t)i0 * (NO * DI * DO);
            #pragma unroll
            for (int it = 0; it < 5; ++it) {
                int f = it * 1024 + tid * 4;
                float4 w4 = *(const float4*)(wg + f);
                int ii   = f / 1280;
                int rem  = f - ii * 1280;
                int j    = rem >> 7;
                int rem2 = rem & 127;
                int e    = rem2 >> 4;
                int d0   = rem2 & 15;
                int base = ((ii * NO + j) * DO + d0) * EP + e;
                wt[base         ] = w4.x;
                wt[base +     EP] = w4.y;
                wt[base + 2 * EP] = w4.z;
                wt[base + 3 * EP] = w4.w;
            }
        }
        __syncthreads();

        for (int ii = 0; ii < TI; ++ii) {
            // u direct from global: 16 lanes per bl-group share the same 16 B
            // (coalesced broadcast); 16 KB/block working set -> L1 hits.
            float ua[DI], ub[DI];
            {
                const float* pa = u0 + (size_t)(i0 + ii) * DI;
                float4 a0 = *(const float4*)(pa);
                float4 a1 = *(const float4*)(pa + 4);
                ua[0]=a0.x; ua[1]=a0.y; ua[2]=a0.z; ua[3]=a0.w;
                ua[4]=a1.x; ua[5]=a1.y; ua[6]=a1.z; ua[7]=a1.w;
                const float* pb = u1 + (size_t)(i0 + ii) * DI;
                float4 b0 = *(const float4*)(pb);
                float4 b1 = *(const float4*)(pb + 4);
                ub[0]=b0.x; ub[1]=b0.y; ub[2]=b0.z; ub[3]=b0.w;
                ub[4]=b1.x; ub[5]=b1.y; ub[6]=b1.z; ub[7]=b1.w;
            }
            float uh0[NO], uh1[NO];
            float c0[NO],  c1[NO];
            #pragma unroll
            for (int j = 0; j < NO; ++j) {
                const float* wr = wt + ((ii * NO + j) * DO + d) * EP;  // 48B rows, 16B aligned
                float4 wA = *(const float4*)(wr);
                float4 wB = *(const float4*)(wr + 4);
                float h0 = ua[0]*wA.x + ua[1]*wA.y + ua[2]*wA.z + ua[3]*wA.w
                         + ua[4]*wB.x + ua[5]*wB.y + ua[6]*wB.z + ua[7]*wB.w;
                float h1 = ub[0]*wA.x + ub[1]*wA.y + ub[2]*wA.z + ub[3]*wA.w
                         + ub[4]*wB.x + ub[5]*wB.y + ub[6]*wB.z + ub[7]*wB.w;
                uh0[j] = h0;
                uh1[j] = h1;
                if (!FIRST) {
                    c0[j] = row_allsum16(h0 * vs0[j]);   // logit[b0,i,j]
                    c1[j] = row_allsum16(h1 * vs1[j]);   // logit[b1,i,j]
                }
            }
            if (FIRST) {
                // b == 0 -> softmax over 10 zeros -> c = 0.1 exactly
                #pragma unroll
                for (int j = 0; j < NO; ++j) {
                    s0[j] += 0.1f * uh0[j];
                    s1[j] += 0.1f * uh1[j];
                }
            } else {
                float m0 = c0[0], m1 = c1[0];
                #pragma unroll
                for (int j = 1; j < NO; ++j) { m0 = fmaxf(m0, c0[j]); m1 = fmaxf(m1, c1[j]); }
                float sum0 = 0.f, sum1 = 0.f;
                #pragma unroll
                for (int j = 0; j < NO; ++j) {
                    float e0 = __expf(c0[j] - m0); c0[j] = e0; sum0 += e0;
                    float e1 = __expf(c1[j] - m1); c1[j] = e1; sum1 += e1;
                }
                float inv0 = 1.f / sum0, inv1 = 1.f / sum1;
                #pragma unroll
                for (int j = 0; j < NO; ++j) {
                    s0[j] += (c0[j] * inv0) * uh0[j];
                    s1[j] += (c1[j] * inv1) * uh1[j];
                }
            }
        }
        __syncthreads();   // protect wt before next chunk's staging
    }

    #pragma unroll
    for (int j = 0; j < NO; ++j) {
        unsafeAtomicAdd(s + ((size_t)bg0 * NO + j) * DO + d, s0[j]);
        unsafeAtomicAdd(s + ((size_t)bg1 * NO + j) * DO + d, s1[j]);
    }
}

// v = squash(s); vsum += v; out = v; s = 0 (ready for next pass)
__global__ void squash_k(float* __restrict__ s, float* __restrict__ vsum,
                         float* __restrict__ out)
{
    int t = blockIdx.x * blockDim.x + threadIdx.x;   // (b*NO + j)
    if (t >= B_ * NO) return;
    float* sp = s + (size_t)t * DO;
    float4 a = *(const float4*)(sp);
    float4 b = *(const float4*)(sp + 4);
    float4 c = *(const float4*)(sp + 8);
    float4 e = *(const float4*)(sp + 12);
    float sq = a.x*a.x + a.y*a.y + a.z*a.z + a.w*a.w
             + b.x*b.x + b.y*b.y + b.z*b.z + b.w*b.w
             + c.x*c.x + c.y*c.y + c.z*c.z + c.w*c.w
             + e.x*e.x + e.y*e.y + e.z*e.z + e.w*e.w;
    float factor = sq / (sqrtf(sq) * (1.f + sq) + 1e-30f);

    float4 va = make_float4(factor*a.x, factor*a.y, factor*a.z, factor*a.w);
    float4 vb = make_float4(factor*b.x, factor*b.y, factor*b.z, factor*b.w);
    float4 vc = make_float4(factor*c.x, factor*c.y, factor*c.z, factor*c.w);
    float4 ve = make_float4(factor*e.x, factor*e.y, factor*e.z, factor*e.w);

    float* op = out + (size_t)t * DO;
    *(float4*)(op)      = va;
    *(float4*)(op + 4)  = vb;
    *(float4*)(op + 8)  = vc;
    *(float4*)(op + 12) = ve;

    float* vp = vsum + (size_t)t * DO;
    float4 p0 = *(const float4*)(vp);
    float4 p1 = *(const float4*)(vp + 4);
    float4 p2 = *(const float4*)(vp + 8);
    float4 p3 = *(const float4*)(vp + 12);
    p0.x += va.x; p0.y += va.y; p0.z += va.z; p0.w += va.w;
    p1.x += vb.x; p1.y += vb.y; p1.z += vb.z; p1.w += vb.w;
    p2.x += vc.x; p2.y += vc.y; p2.z += vc.z; p2.w += vc.w;
    p3.x += ve.x; p3.y += ve.y; p3.z += ve.z; p3.w += ve.w;
    *(float4*)(vp)      = p0;
    *(float4*)(vp + 4)  = p1;
    *(float4*)(vp + 8)  = p2;
    *(float4*)(vp + 12) = p3;

    float4 z = make_float4(0.f, 0.f, 0.f, 0.f);
    *(float4*)(sp)      = z;
    *(float4*)(sp + 4)  = z;
    *(float4*)(sp + 8)  = z;
    *(float4*)(sp + 12) = z;
}

extern "C" void kernel_launch(void* const* d_in, const int* in_sizes, int n_in,
                              void* d_out, int out_size, void* d_ws, size_t ws_size,
                              hipStream_t stream)
{
    (void)in_sizes; (void)n_in; (void)out_size; (void)ws_size;
    const float* u = (const float*)d_in[0];
    const float* W = (const float*)d_in[1];
    // d_in[2] is r; fixed at 3 by the reference setup -> 3 unrolled rounds below.
    float* out  = (float*)d_out;
    float* s    = (float*)d_ws;                 // [512,10,16]
    float* vsum = s + B_ * NO * DO;             // [512,10,16]

    hipMemsetAsync(d_ws, 0, (size_t)2 * B_ * NO * DO * sizeof(float), stream);

    dim3 grid(IGROUPS, B_ / TB), blk(256);     // 72 x 16 = 1152 blocks, 5/CU resident
    dim3 sg((B_ * NO + 255) / 256), sb(256);

    routing_pass<true ><<<grid, blk, 0, stream>>>(u, W, vsum, s);
    squash_k<<<sg, sb, 0, stream>>>(s, vsum, out);
    routing_pass<false><<<grid, blk, 0, stream>>>(u, W, vsum, s);
    squash_k<<<sg, sb, 0, stream>>>(s, vsum, out);
    routing_pass<false><<<grid, blk, 0, stream>>>(u, W, vsum, s);
    squash_k<<<sg, sb, 0, stream>>>(s, vsum, out);
}

// Round 9
// 314.472 us; speedup vs baseline: 1.5493x; 1.5493x over previous
//
#include <hip/hip_runtime.h>
#include <math.h>

// DigitCaps dynamic routing, fused/recompute formulation.
// u: [512,1152,8] f32, W: [1152,10,8,16] f32, out v: [512,10,16] f32.
// u_hat is NEVER materialized (377 MB). Routing logits are linear in v:
//   b_t[b,i,j] = sum_d u_hat[b,i,j,d] * Vsum[b,j,d],  Vsum = v1+...+v_{t-1}
// so each pass recomputes u_hat once from u,W and needs only Vsum (327 KB).
//
// R9: revert to the measured champion (R1 kernel, 316.5 us total,
// 105 us/pass, FETCH 65 MB / WRITE 79 MB, VGPR 64 — clean codegen).
// Session evidence: every structural deviation from this shape tripped the
// compiler's register-pressure cliff into a scratch-traffic storm:
//   - TI=3 guarded staging (R4/R5): 454/800 MB, 312 us/pass
//   - register prefetch across compute (R7): WRITE 189 MB, 123 us/pass
//   - u direct-from-global + lb(256,5) (R8): 320/600 MB, 248 us/pass
// Clean-codegen invariants (do not violate): TI=4 unguarded staging,
// u staged in LDS, launch_bounds(256,4), no long float4 live ranges
// across the compute loop, no staging guards.

#define B_  512
#define NI  1152
#define NO  10
#define DI  8
#define DO  16

constexpr int TB      = 32;              // batches per block (2 per thread)
constexpr int TI      = 4;               // i's per staged chunk
constexpr int CHUNKS  = 2;               // kept for doc; loop below uses 4 chunks of TI=4
constexpr int NCHUNK  = 4;               // chunks per block -> 16 i per block
constexpr int IGROUPS = NI / (TI * NCHUNK);   // 72
constexpr int EP      = 12;              // padded e-stride: rows 48B -> 16B aligned
constexpr int USTRIDE = 36;              // padded per-batch u row (32 used)

// LDS: Wt 4*10*16*12 = 7680 f (30720 B) + u 32*36 = 1152 f (4608 B) = 35328 B
// -> 4 blocks/CU, VGPR 64 (measured), clean codegen.

// all-lanes sum over each aligned 16-lane group (d-lanes), DPP only (no LDS traffic)
__device__ __forceinline__ float row_allsum16(float x)
{
    union F { float f; int i; } a, t;
    a.f = x;  // quad_perm [1,0,3,2] : xor 1
    t.i = __builtin_amdgcn_update_dpp(0, a.i, 0xB1, 0xF, 0xF, true);  x += t.f;
    a.f = x;  // quad_perm [2,3,0,1] : xor 2
    t.i = __builtin_amdgcn_update_dpp(0, a.i, 0x4E, 0xF, 0xF, true);  x += t.f;
    a.f = x;  // row_ror:4
    t.i = __builtin_amdgcn_update_dpp(0, a.i, 0x124, 0xF, 0xF, true); x += t.f;
    a.f = x;  // row_ror:8
    t.i = __builtin_amdgcn_update_dpp(0, a.i, 0x128, 0xF, 0xF, true); x += t.f;
    return x; // every lane in the 16-group now holds the full 16-sum
}

template<bool FIRST>
__global__ __launch_bounds__(256, 4)
void routing_pass(const float* __restrict__ u, const float* __restrict__ W,
                  const float* __restrict__ vsum, float* __restrict__ s)
{
    __shared__ float wt[TI * NO * DO * EP];   // 7680 floats
    __shared__ float ul[TB * USTRIDE];        // 1152 floats

    const int tid = threadIdx.x;
    const int bl  = tid >> 4;      // local batch slot 0..15
    const int d   = tid & 15;      // output dim 0..15
    const int bg0 = blockIdx.y * TB + bl;
    const int bg1 = bg0 + 16;

    float vs0[NO], vs1[NO];
    if (!FIRST) {
        #pragma unroll
        for (int j = 0; j < NO; ++j) {
            vs0[j] = vsum[((size_t)bg0 * NO + j) * DO + d];
            vs1[j] = vsum[((size_t)bg1 * NO + j) * DO + d];
        }
    }
    float s0[NO], s1[NO];
    #pragma unroll
    for (int j = 0; j < NO; ++j) { s0[j] = 0.f; s1[j] = 0.f; }

    for (int c = 0; c < NCHUNK; ++c) {
        const int i0 = (blockIdx.x + c * IGROUPS) * TI;

        // ---- stage W chunk (contiguous 5120 floats) into LDS, transposed to
        //      wt[((ii*10+j)*16+d)*EP + e] so each thread reads its 8 e's contiguously
        {
            const float* wg = W + (size_t)i0 * (NO * DI * DO);
            #pragma unroll
            for (int it = 0; it < 5; ++it) {
                int f = it * 1024 + tid * 4;
                float4 w4 = *(const float4*)(wg + f);
                int ii   = f / 1280;
                int rem  = f - ii * 1280;
                int j    = rem >> 7;
                int rem2 = rem & 127;
                int e    = rem2 >> 4;
                int d0   = rem2 & 15;
                int base = ((ii * NO + j) * DO + d0) * EP + e;
                wt[base         ] = w4.x;
                wt[base +     EP] = w4.y;
                wt[base + 2 * EP] = w4.z;
                wt[base + 3 * EP] = w4.w;
            }
            // ---- stage u tile: 32 b x 4 i x 8 e = 1024 floats
            int f   = tid * 4;
            int ubl = f >> 5;          // 32 floats per batch row
            int off = f & 31;
            float4 u4 = *(const float4*)(u + (size_t)(blockIdx.y * TB + ubl) * (NI * DI)
                                           + (size_t)i0 * DI + off);
            *(float4*)(ul + ubl * USTRIDE + off) = u4;
        }
        __syncthreads();

        for (int ii = 0; ii < TI; ++ii) {
            float ua[DI], ub[DI];
            {
                float4 a0 = *(const float4*)(ul + bl * USTRIDE + ii * DI);
                float4 a1 = *(const float4*)(ul + bl * USTRIDE + ii * DI + 4);
                ua[0]=a0.x; ua[1]=a0.y; ua[2]=a0.z; ua[3]=a0.w;
                ua[4]=a1.x; ua[5]=a1.y; ua[6]=a1.z; ua[7]=a1.w;
                float4 b0 = *(const float4*)(ul + (bl + 16) * USTRIDE + ii * DI);
                float4 b1 = *(const float4*)(ul + (bl + 16) * USTRIDE + ii * DI + 4);
                ub[0]=b0.x; ub[1]=b0.y; ub[2]=b0.z; ub[3]=b0.w;
                ub[4]=b1.x; ub[5]=b1.y; ub[6]=b1.z; ub[7]=b1.w;
            }
            float uh0[NO], uh1[NO];
            float c0[NO],  c1[NO];
            #pragma unroll
            for (int j = 0; j < NO; ++j) {
                const float* wr = wt + ((ii * NO + j) * DO + d) * EP;
                float4 wA = *(const float4*)(wr);      // 16B aligned (EP=12 -> 48B rows)
                float4 wB = *(const float4*)(wr + 4);
                float h0 = ua[0]*wA.x + ua[1]*wA.y + ua[2]*wA.z + ua[3]*wA.w
                         + ua[4]*wB.x + ua[5]*wB.y + ua[6]*wB.z + ua[7]*wB.w;
                float h1 = ub[0]*wA.x + ub[1]*wA.y + ub[2]*wA.z + ub[3]*wA.w
                         + ub[4]*wB.x + ub[5]*wB.y + ub[6]*wB.z + ub[7]*wB.w;
                uh0[j] = h0;
                uh1[j] = h1;
                if (!FIRST) {
                    c0[j] = row_allsum16(h0 * vs0[j]);   // logit[b0,i,j]
                    c1[j] = row_allsum16(h1 * vs1[j]);   // logit[b1,i,j]
                }
            }
            if (FIRST) {
                // b == 0 -> softmax over 10 zeros -> c = 0.1 exactly
                #pragma unroll
                for (int j = 0; j < NO; ++j) {
                    s0[j] += 0.1f * uh0[j];
                    s1[j] += 0.1f * uh1[j];
                }
            } else {
                float m0 = c0[0], m1 = c1[0];
                #pragma unroll
                for (int j = 1; j < NO; ++j) { m0 = fmaxf(m0, c0[j]); m1 = fmaxf(m1, c1[j]); }
                float sum0 = 0.f, sum1 = 0.f;
                #pragma unroll
                for (int j = 0; j < NO; ++j) {
                    float e0 = __expf(c0[j] - m0); c0[j] = e0; sum0 += e0;
                    float e1 = __expf(c1[j] - m1); c1[j] = e1; sum1 += e1;
                }
                float inv0 = 1.f / sum0, inv1 = 1.f / sum1;
                #pragma unroll
                for (int j = 0; j < NO; ++j) {
                    s0[j] += (c0[j] * inv0) * uh0[j];
                    s1[j] += (c1[j] * inv1) * uh1[j];
                }
            }
        }
        __syncthreads();   // protect LDS before next chunk's staging
    }

    #pragma unroll
    for (int j = 0; j < NO; ++j) {
        unsafeAtomicAdd(s + ((size_t)bg0 * NO + j) * DO + d, s0[j]);
        unsafeAtomicAdd(s + ((size_t)bg1 * NO + j) * DO + d, s1[j]);
    }
}

// v = squash(s); vsum += v; out = v; s = 0 (ready for next pass)
__global__ void squash_k(float* __restrict__ s, float* __restrict__ vsum,
                         float* __restrict__ out)
{
    int t = blockIdx.x * blockDim.x + threadIdx.x;   // (b*NO + j)
    if (t >= B_ * NO) return;
    float* sp = s + (size_t)t * DO;
    float4 a = *(const float4*)(sp);
    float4 b = *(const float4*)(sp + 4);
    float4 c = *(const float4*)(sp + 8);
    float4 e = *(const float4*)(sp + 12);
    float sq = a.x*a.x + a.y*a.y + a.z*a.z + a.w*a.w
             + b.x*b.x + b.y*b.y + b.z*b.z + b.w*b.w
             + c.x*c.x + c.y*c.y + c.z*c.z + c.w*c.w
             + e.x*e.x + e.y*e.y + e.z*e.z + e.w*e.w;
    float factor = sq / (sqrtf(sq) * (1.f + sq) + 1e-30f);

    float4 va = make_float4(factor*a.x, factor*a.y, factor*a.z, factor*a.w);
    float4 vb = make_float4(factor*b.x, factor*b.y, factor*b.z, factor*b.w);
    float4 vc = make_float4(factor*c.x, factor*c.y, factor*c.z, factor*c.w);
    float4 ve = make_float4(factor*e.x, factor*e.y, factor*e.z, factor*e.w);

    float* op = out + (size_t)t * DO;
    *(float4*)(op)      = va;
    *(float4*)(op + 4)  = vb;
    *(float4*)(op + 8)  = vc;
    *(float4*)(op + 12) = ve;

    float* vp = vsum + (size_t)t * DO;
    float4 p0 = *(const float4*)(vp);
    float4 p1 = *(const float4*)(vp + 4);
    float4 p2 = *(const float4*)(vp + 8);
    float4 p3 = *(const float4*)(vp + 12);
    p0.x += va.x; p0.y += va.y; p0.z += va.z; p0.w += va.w;
    p1.x += vb.x; p1.y += vb.y; p1.z += vb.z; p1.w += vb.w;
    p2.x += vc.x; p2.y += vc.y; p2.z += vc.z; p2.w += vc.w;
    p3.x += ve.x; p3.y += ve.y; p3.z += ve.z; p3.w += ve.w;
    *(float4*)(vp)      = p0;
    *(float4*)(vp + 4)  = p1;
    *(float4*)(vp + 8)  = p2;
    *(float4*)(vp + 12) = p3;

    float4 z = make_float4(0.f, 0.f, 0.f, 0.f);
    *(float4*)(sp)      = z;
    *(float4*)(sp + 4)  = z;
    *(float4*)(sp + 8)  = z;
    *(float4*)(sp + 12) = z;
}

extern "C" void kernel_launch(void* const* d_in, const int* in_sizes, int n_in,
                              void* d_out, int out_size, void* d_ws, size_t ws_size,
                              hipStream_t stream)
{
    (void)in_sizes; (void)n_in; (void)out_size; (void)ws_size;
    const float* u = (const float*)d_in[0];
    const float* W = (const float*)d_in[1];
    // d_in[2] is r; fixed at 3 by the reference setup -> 3 unrolled rounds below.
    float* out  = (float*)d_out;
    float* s    = (float*)d_ws;                 // [512,10,16]
    float* vsum = s + B_ * NO * DO;             // [512,10,16]

    hipMemsetAsync(d_ws, 0, (size_t)2 * B_ * NO * DO * sizeof(float), stream);

    dim3 grid(IGROUPS, B_ / TB), blk(256);
    dim3 sg((B_ * NO + 255) / 256), sb(256);

    routing_pass<true ><<<grid, blk, 0, stream>>>(u, W, vsum, s);
    squash_k<<<sg, sb, 0, stream>>>(s, vsum, out);
    routing_pass<false><<<grid, blk, 0, stream>>>(u, W, vsum, s);
    squash_k<<<sg, sb, 0, stream>>>(s, vsum, out);
    routing_pass<false><<<grid, blk, 0, stream>>>(u, W, vsum, s);
    squash_k<<<sg, sb, 0, stream>>>(s, vsum, out);
}